// Round 2
// baseline (515.269 us; speedup 1.0000x reference)
//
#include <hip/hip_runtime.h>
#include <hip/hip_bf16.h>
#include <hip/hip_fp16.h>

// Problem constants
#define B_    8
#define L_    16384
#define CIN_  256
#define COUT_ 256
#define LS_   4096
#define H_    4
#define D_    64

typedef _Float16 f16x8 __attribute__((ext_vector_type(8)));
typedef _Float16 f16x4 __attribute__((ext_vector_type(4)));
typedef float    f32x4 __attribute__((ext_vector_type(4)));

// ---------------------------------------------------------------------------
// K1: max-pool over S=4 and convert to fp16.  x (B,L,256) f32 -> xp (B*LS,256) f16
// ---------------------------------------------------------------------------
__global__ __launch_bounds__(256) void k1_pool(const float* __restrict__ x,
                                               _Float16* __restrict__ xp) {
    int idx = blockIdx.x * 256 + threadIdx.x;   // over 32768 * 64 float4-chunks
    int c4  = idx & 63;                         // which float4 within the row
    int bp  = idx >> 6;                         // pooled row index (b*4096+lp)
    int b   = bp >> 12;
    int lp  = bp & 4095;
    const float4* base = (const float4*)(x + ((size_t)(b * L_ + lp * 4)) * CIN_) + c4;
    float4 m = base[0];
    #pragma unroll
    for (int s = 1; s < 4; ++s) {
        float4 v = base[s * 64];               // next l row = 256 floats = 64 float4
        m.x = fmaxf(m.x, v.x); m.y = fmaxf(m.y, v.y);
        m.z = fmaxf(m.z, v.z); m.w = fmaxf(m.w, v.w);
    }
    f16x4 h;
    h[0] = (_Float16)m.x; h[1] = (_Float16)m.y;
    h[2] = (_Float16)m.z; h[3] = (_Float16)m.w;
    *(f16x4*)(xp + (size_t)bp * CIN_ + c4 * 4) = h;
}

// ---------------------------------------------------------------------------
// K1b: Wa|Wb (256x256 f32, [k][n]) -> WabT (512x256 f16, [n][k])  (biases cancel)
// ---------------------------------------------------------------------------
__global__ __launch_bounds__(256) void k1b_wcvt(const float* __restrict__ Wa,
                                                const float* __restrict__ Wb,
                                                _Float16* __restrict__ WabT) {
    int n = blockIdx.x;            // 0..511  (0-255 -> Wa cols, 256-511 -> Wb cols)
    int k = threadIdx.x;           // 0..255
    const float* W = (n < 256) ? Wa : Wb;
    int nn = n & 255;
    WabT[(size_t)n * 256 + k] = (_Float16)W[(size_t)k * 256 + nn];
}

// ---------------------------------------------------------------------------
// K2: logits GEMM.  C = xp @ [Wa|Wb]   (M=32768, N=512, K=256), f16 MFMA,
// LDS-free, writes TRANSPOSED: xabT[b][col(0..511)][l(0..4095)] f32.
// Per block: 64 rows x 256 cols (one n-half), 4 waves of 64x64.
// ---------------------------------------------------------------------------
__global__ __launch_bounds__(256) void k2_gemm_ab(const _Float16* __restrict__ xp,
                                                  const _Float16* __restrict__ WabT,
                                                  float* __restrict__ xabT) {
    int rowtile = blockIdx.x;            // 0..511
    int nhalf   = blockIdx.y;            // 0..1
    int row0    = rowtile * 64;
    int wave = threadIdx.x >> 6;
    int lane = threadIdx.x & 63;
    int lr = lane & 15, lg = lane >> 4;
    int col0 = wave * 64;                // within the 256-col half
    const _Float16* Bbase = WabT + (size_t)(nhalf * 256) * 256;

    f32x4 acc[4][4] = {};
    for (int kk = 0; kk < 256; kk += 32) {
        f16x8 af[4], bf[4];
        #pragma unroll
        for (int t = 0; t < 4; ++t)
            af[t] = *(const f16x8*)(xp + (size_t)(row0 + t * 16 + lr) * 256 + kk + lg * 8);
        #pragma unroll
        for (int t = 0; t < 4; ++t)
            bf[t] = *(const f16x8*)(Bbase + (size_t)(col0 + t * 16 + lr) * 256 + kk + lg * 8);
        #pragma unroll
        for (int rt = 0; rt < 4; ++rt)
            #pragma unroll
            for (int ct = 0; ct < 4; ++ct)
                acc[rt][ct] = __builtin_amdgcn_mfma_f32_16x16x32_f16(af[rt], bf[ct], acc[rt][ct], 0, 0, 0);
    }
    // Transposed store: C/D frag rows (lg*4 + reg) are 4 consecutive l -> f32x4 store
    int b  = row0 >> 12;
    int l0 = row0 & 4095;
    #pragma unroll
    for (int rt = 0; rt < 4; ++rt)
        #pragma unroll
        for (int ct = 0; ct < 4; ++ct) {
            int colg  = nhalf * 256 + col0 + ct * 16 + lr;
            int lbase = l0 + rt * 16 + lg * 4;
            *(f32x4*)(xabT + ((size_t)b * 512 + colg) * 4096 + lbase) = acc[rt][ct];
        }
}

// ---------------------------------------------------------------------------
// K3: per (b,h,d): softmax over l of a-logits, fused with the roll-diff dot:
//   s = ( sum_l e_l * (xb[l] - xb[(l+d)%4096]) ) / ( sum_l e_l )
// ---------------------------------------------------------------------------
__global__ __launch_bounds__(256) void k3_softmax(const float* __restrict__ xabT,
                                                  float* __restrict__ s) {
    int bid = blockIdx.x;               // 0..2047 = b*256 + ch
    int b = bid >> 8, ch = bid & 255, d = ch & 63;
    const float* arow = xabT + ((size_t)b * 512 + ch) * 4096;
    const float* brow = xabT + ((size_t)b * 512 + 256 + ch) * 4096;
    int t = threadIdx.x;

    __shared__ float wm[4], wz[4], ww[4];

    float m = -INFINITY;
    for (int l = t; l < 4096; l += 256) m = fmaxf(m, arow[l]);
    #pragma unroll
    for (int off = 32; off; off >>= 1) m = fmaxf(m, __shfl_xor(m, off));
    if ((t & 63) == 0) wm[t >> 6] = m;
    __syncthreads();
    m = fmaxf(fmaxf(wm[0], wm[1]), fmaxf(wm[2], wm[3]));

    float Z = 0.f, W = 0.f;
    for (int l = t; l < 4096; l += 256) {
        float e = __expf(arow[l] - m);
        Z += e;
        W += e * (brow[l] - brow[(l + d) & 4095]);
    }
    #pragma unroll
    for (int off = 32; off; off >>= 1) {
        Z += __shfl_xor(Z, off);
        W += __shfl_xor(W, off);
    }
    if ((t & 63) == 0) { wz[t >> 6] = Z; ww[t >> 6] = W; }
    __syncthreads();
    if (t == 0) {
        float Zs = wz[0] + wz[1] + wz[2] + wz[3];
        float Ws = ww[0] + ww[1] + ww[2] + ww[3];
        s[bid] = Ws / Zs;
    }
}

// ---------------------------------------------------------------------------
// K4: per batch: M_b = Wc * diag(s_b) * Wo2,  v_b = (bc .* s_b) @ Wo2 + bo
//     Wo2[j,:] = Wo[(j%64)*4 + j/64, :].  Output MT fp16 [b][n][i] (+ v f32).
// grid (8, 16): blockIdx.x=b, blockIdx.y=i-tile of 16. 256 threads = n.
// ---------------------------------------------------------------------------
__global__ __launch_bounds__(256) void k4_buildM(const float* __restrict__ Wc,
                                                 const float* __restrict__ bc,
                                                 const float* __restrict__ Wo,
                                                 const float* __restrict__ bo,
                                                 const float* __restrict__ s,
                                                 _Float16* __restrict__ MT,
                                                 float* __restrict__ v) {
    int b = blockIdx.x, it = blockIdx.y;
    int i0 = it * 16;
    int n  = threadIdx.x;

    __shared__ float wc[16][257];
    __shared__ float sl[256], bcl[256];
    sl[n]  = s[b * 256 + n];
    bcl[n] = bc[n];
    #pragma unroll
    for (int ii = 0; ii < 16; ++ii) wc[ii][n] = Wc[(size_t)(i0 + ii) * 256 + n];
    __syncthreads();

    float acc[16] = {};
    float accv = 0.f;
    for (int j = 0; j < 256; ++j) {
        int pj = ((j & 63) << 2) | (j >> 6);       // perm(j) = (j%64)*4 + j/64
        float wo  = Wo[(size_t)pj * 256 + n];
        float tmp = sl[j] * wo;
        #pragma unroll
        for (int ii = 0; ii < 16; ++ii) acc[ii] += wc[ii][j] * tmp;
        accv += bcl[j] * tmp;
    }
    #pragma unroll
    for (int ii = 0; ii < 16; ++ii)
        MT[((size_t)b * 256 + n) * 256 + i0 + ii] = (_Float16)acc[ii];
    if (it == 0) v[b * 256 + n] = accv + bo[n];
}

// ---------------------------------------------------------------------------
// K5: main GEMM.  out[b] = x[b] @ M_b + v_b   (131072 x 256 x 256), f16 MFMA,
// x converted f32->f16 on the fly. LDS-free; B frags direct from L2-resident MT.
// Block: 64 rows x 256 cols, 4 waves of 64x64.
// ---------------------------------------------------------------------------
__global__ __launch_bounds__(256) void k5_main(const float* __restrict__ x,
                                               const _Float16* __restrict__ MT,
                                               const float* __restrict__ v,
                                               float* __restrict__ out) {
    int bid  = blockIdx.x;               // 0..2047
    int b    = bid >> 8;
    int row0 = bid * 64;                 // global row in [0, 131072)
    int wave = threadIdx.x >> 6, lane = threadIdx.x & 63;
    int lr = lane & 15, lg = lane >> 4;
    int col0 = wave * 64;
    const _Float16* Bb = MT + (size_t)b * 256 * 256;

    f32x4 acc[4][4] = {};
    for (int kk = 0; kk < 256; kk += 32) {
        f16x8 af[4], bf[4];
        #pragma unroll
        for (int t = 0; t < 4; ++t) {
            const float* ap = x + (size_t)(row0 + t * 16 + lr) * 256 + kk + lg * 8;
            float4 f0 = *(const float4*)ap;
            float4 f1 = *(const float4*)(ap + 4);
            f16x8 a;
            a[0] = (_Float16)f0.x; a[1] = (_Float16)f0.y;
            a[2] = (_Float16)f0.z; a[3] = (_Float16)f0.w;
            a[4] = (_Float16)f1.x; a[5] = (_Float16)f1.y;
            a[6] = (_Float16)f1.z; a[7] = (_Float16)f1.w;
            af[t] = a;
        }
        #pragma unroll
        for (int t = 0; t < 4; ++t)
            bf[t] = *(const f16x8*)(Bb + (size_t)(col0 + t * 16 + lr) * 256 + kk + lg * 8);
        #pragma unroll
        for (int rt = 0; rt < 4; ++rt)
            #pragma unroll
            for (int ct = 0; ct < 4; ++ct)
                acc[rt][ct] = __builtin_amdgcn_mfma_f32_16x16x32_f16(af[rt], bf[ct], acc[rt][ct], 0, 0, 0);
    }
    #pragma unroll
    for (int ct = 0; ct < 4; ++ct) {
        int n = col0 + ct * 16 + lr;
        float vb = v[b * 256 + n];
        #pragma unroll
        for (int rt = 0; rt < 4; ++rt) {
            int r = row0 + rt * 16 + lg * 4;
            float* o = out + (size_t)r * 256 + n;
            #pragma unroll
            for (int reg = 0; reg < 4; ++reg)
                o[(size_t)reg * 256] = acc[rt][ct][reg] + vb;
        }
    }
}

// ---------------------------------------------------------------------------
extern "C" void kernel_launch(void* const* d_in, const int* in_sizes, int n_in,
                              void* d_out, int out_size, void* d_ws, size_t ws_size,
                              hipStream_t stream) {
    const float* x  = (const float*)d_in[0];
    const float* Wa = (const float*)d_in[1];
    // const float* ba = (const float*)d_in[2];   // cancels in softmax
    const float* Wb = (const float*)d_in[3];
    // const float* bb = (const float*)d_in[4];   // cancels in roll-difference
    const float* Wc = (const float*)d_in[5];
    const float* bc = (const float*)d_in[6];
    const float* Wo = (const float*)d_in[7];
    const float* bo = (const float*)d_in[8];
    float* out = (float*)d_out;

    // Workspace (small buffers only; ~18 MB total):
    char* w = (char*)d_ws;
    _Float16* xp   = (_Float16*)w;  w += (size_t)32768 * 256 * 2;        // 16.8 MB
    _Float16* WabT = (_Float16*)w;  w += (size_t)512 * 256 * 2;          // 256 KB
    float*    s    = (float*)w;     w += (size_t)8 * 256 * 4;
    _Float16* MT   = (_Float16*)w;  w += (size_t)8 * 256 * 256 * 2;      // 1 MB
    float*    vb   = (float*)w;     w += (size_t)8 * 256 * 4;

    // Large xabT intermediate (67 MB) lives in d_out (134 MB): it is fully
    // consumed by k3 before k5 overwrites d_out with the real output.
    float* xabT = out;

    k1_pool  <<<8192, 256, 0, stream>>>(x, xp);
    k1b_wcvt <<<512, 256, 0, stream>>>(Wa, Wb, WabT);
    k2_gemm_ab<<<dim3(512, 2), 256, 0, stream>>>(xp, WabT, xabT);
    k3_softmax<<<2048, 256, 0, stream>>>(xabT, s);
    k4_buildM <<<dim3(8, 16), 256, 0, stream>>>(Wc, bc, Wo, bo, s, MT, vb);
    k5_main   <<<2048, 256, 0, stream>>>(x, MT, vb, out);
}

// Round 3
// 426.219 us; speedup vs baseline: 1.2089x; 1.2089x over previous
//
#include <hip/hip_runtime.h>
#include <hip/hip_bf16.h>
#include <hip/hip_fp16.h>

// Problem constants
#define B_    8
#define L_    16384
#define CIN_  256
#define COUT_ 256
#define LS_   4096
#define H_    4
#define D_    64

typedef _Float16 f16x8 __attribute__((ext_vector_type(8)));
typedef _Float16 f16x4 __attribute__((ext_vector_type(4)));
typedef float    f32x4 __attribute__((ext_vector_type(4)));

// ---------------------------------------------------------------------------
// K1: max-pool over S=4 and convert to fp16.  x (B,L,256) f32 -> xp (B*LS,256) f16
// ---------------------------------------------------------------------------
__global__ __launch_bounds__(256) void k1_pool(const float* __restrict__ x,
                                               _Float16* __restrict__ xp) {
    int idx = blockIdx.x * 256 + threadIdx.x;   // over 32768 * 64 float4-chunks
    int c4  = idx & 63;                         // which float4 within the row
    int bp  = idx >> 6;                         // pooled row index (b*4096+lp)
    int b   = bp >> 12;
    int lp  = bp & 4095;
    const float4* base = (const float4*)(x + ((size_t)(b * L_ + lp * 4)) * CIN_) + c4;
    float4 m = base[0];
    #pragma unroll
    for (int s = 1; s < 4; ++s) {
        float4 v = base[s * 64];               // next l row = 256 floats = 64 float4
        m.x = fmaxf(m.x, v.x); m.y = fmaxf(m.y, v.y);
        m.z = fmaxf(m.z, v.z); m.w = fmaxf(m.w, v.w);
    }
    f16x4 h;
    h[0] = (_Float16)m.x; h[1] = (_Float16)m.y;
    h[2] = (_Float16)m.z; h[3] = (_Float16)m.w;
    *(f16x4*)(xp + (size_t)bp * CIN_ + c4 * 4) = h;
}

// ---------------------------------------------------------------------------
// K1b: Wa|Wb (256x256 f32, [k][n]) -> WabT (512x256 f16, [n][k])  (biases cancel)
//      + Wc (256x256 f32 row-major) -> Wc16 (f16 row-major)
// ---------------------------------------------------------------------------
__global__ __launch_bounds__(256) void k1b_wcvt(const float* __restrict__ Wa,
                                                const float* __restrict__ Wb,
                                                const float* __restrict__ Wc,
                                                _Float16* __restrict__ WabT,
                                                _Float16* __restrict__ Wc16) {
    int n = blockIdx.x;            // 0..767
    int k = threadIdx.x;           // 0..255
    if (n < 512) {
        const float* W = (n < 256) ? Wa : Wb;
        int nn = n & 255;
        WabT[(size_t)n * 256 + k] = (_Float16)W[(size_t)k * 256 + nn];
    } else {
        int r = n - 512;
        Wc16[(size_t)r * 256 + k] = (_Float16)Wc[(size_t)r * 256 + k];
    }
}

// ---------------------------------------------------------------------------
// K2: logits GEMM.  C = xp @ [Wa|Wb]   (M=32768, N=512, K=256), f16 MFMA,
// LDS-free, writes TRANSPOSED: xabT[b][col(0..511)][l(0..4095)] f32.
// Per block: 64 rows x 256 cols (one n-half), 4 waves of 64x64.
// ---------------------------------------------------------------------------
__global__ __launch_bounds__(256) void k2_gemm_ab(const _Float16* __restrict__ xp,
                                                  const _Float16* __restrict__ WabT,
                                                  float* __restrict__ xabT) {
    int rowtile = blockIdx.x;            // 0..511
    int nhalf   = blockIdx.y;            // 0..1
    int row0    = rowtile * 64;
    int wave = threadIdx.x >> 6;
    int lane = threadIdx.x & 63;
    int lr = lane & 15, lg = lane >> 4;
    int col0 = wave * 64;                // within the 256-col half
    const _Float16* Bbase = WabT + (size_t)(nhalf * 256) * 256;

    f32x4 acc[4][4] = {};
    for (int kk = 0; kk < 256; kk += 32) {
        f16x8 af[4], bf[4];
        #pragma unroll
        for (int t = 0; t < 4; ++t)
            af[t] = *(const f16x8*)(xp + (size_t)(row0 + t * 16 + lr) * 256 + kk + lg * 8);
        #pragma unroll
        for (int t = 0; t < 4; ++t)
            bf[t] = *(const f16x8*)(Bbase + (size_t)(col0 + t * 16 + lr) * 256 + kk + lg * 8);
        #pragma unroll
        for (int rt = 0; rt < 4; ++rt)
            #pragma unroll
            for (int ct = 0; ct < 4; ++ct)
                acc[rt][ct] = __builtin_amdgcn_mfma_f32_16x16x32_f16(af[rt], bf[ct], acc[rt][ct], 0, 0, 0);
    }
    // Transposed store: C/D frag rows (lg*4 + reg) are 4 consecutive l -> f32x4 store
    int b  = row0 >> 12;
    int l0 = row0 & 4095;
    #pragma unroll
    for (int rt = 0; rt < 4; ++rt)
        #pragma unroll
        for (int ct = 0; ct < 4; ++ct) {
            int colg  = nhalf * 256 + col0 + ct * 16 + lr;
            int lbase = l0 + rt * 16 + lg * 4;
            *(f32x4*)(xabT + ((size_t)b * 512 + colg) * 4096 + lbase) = acc[rt][ct];
        }
}

// ---------------------------------------------------------------------------
// K3: per (b,h,d): softmax over l of a-logits, fused with the roll-diff dot:
//   s = ( sum_l e_l * (xb[l] - xb[(l+d)%4096]) ) / ( sum_l e_l )
// ---------------------------------------------------------------------------
__global__ __launch_bounds__(256) void k3_softmax(const float* __restrict__ xabT,
                                                  float* __restrict__ s) {
    int bid = blockIdx.x;               // 0..2047 = b*256 + ch
    int b = bid >> 8, ch = bid & 255, d = ch & 63;
    const float* arow = xabT + ((size_t)b * 512 + ch) * 4096;
    const float* brow = xabT + ((size_t)b * 512 + 256 + ch) * 4096;
    int t = threadIdx.x;

    __shared__ float wm[4], wz[4], ww[4];

    float m = -INFINITY;
    for (int l = t; l < 4096; l += 256) m = fmaxf(m, arow[l]);
    #pragma unroll
    for (int off = 32; off; off >>= 1) m = fmaxf(m, __shfl_xor(m, off));
    if ((t & 63) == 0) wm[t >> 6] = m;
    __syncthreads();
    m = fmaxf(fmaxf(wm[0], wm[1]), fmaxf(wm[2], wm[3]));

    float Z = 0.f, W = 0.f;
    for (int l = t; l < 4096; l += 256) {
        float e = __expf(arow[l] - m);
        Z += e;
        W += e * (brow[l] - brow[(l + d) & 4095]);
    }
    #pragma unroll
    for (int off = 32; off; off >>= 1) {
        Z += __shfl_xor(Z, off);
        W += __shfl_xor(W, off);
    }
    if ((t & 63) == 0) { wz[t >> 6] = Z; ww[t >> 6] = W; }
    __syncthreads();
    if (t == 0) {
        float Zs = wz[0] + wz[1] + wz[2] + wz[3];
        float Ws = ww[0] + ww[1] + ww[2] + ww[3];
        s[bid] = Ws / Zs;
    }
}

// ---------------------------------------------------------------------------
// K4a: per batch: WoBs[b][n][j] = f16( s[b,j] * Wo[perm(j)][n] )   (B operand,
//      [n][j] layout, j contiguous) and v[b][n] = sum_j bc[j]*s*Wo2[j][n] + bo.
// grid (8), 256 threads = n.  All loads coalesced (threads share j).
// ---------------------------------------------------------------------------
__global__ __launch_bounds__(256) void k4a_scale(const float* __restrict__ Wo,
                                                 const float* __restrict__ bc,
                                                 const float* __restrict__ bo,
                                                 const float* __restrict__ s,
                                                 _Float16* __restrict__ WoBs,
                                                 float* __restrict__ v) {
    int b = blockIdx.x;
    int n = threadIdx.x;
    __shared__ float sl[256], bcl[256];
    sl[n]  = s[b * 256 + n];
    bcl[n] = bc[n];
    __syncthreads();

    float accv = 0.f;
    _Float16* dst = WoBs + ((size_t)(b * 256 + n)) * 256;
    for (int j0 = 0; j0 < 256; j0 += 8) {
        f16x8 pack;
        #pragma unroll
        for (int e = 0; e < 8; ++e) {
            int j  = j0 + e;
            int pj = ((j & 63) << 2) | (j >> 6);      // perm(j) = (j%64)*4 + j/64
            float wo  = Wo[(size_t)pj * 256 + n];
            float val = sl[j] * wo;
            accv += bcl[j] * val;
            pack[e] = (_Float16)val;
        }
        *(f16x8*)(dst + j0) = pack;
    }
    v[b * 256 + n] = accv + bo[n];
}

// ---------------------------------------------------------------------------
// K4b: MFMA build of M_b = Wc @ diag(s_b) @ Wo2 using Wc16 (A, row-major [i][k])
//      and WoBs[b] (B, [n][k]).  Output MT f16 [b][n][i] (i contiguous, ready
//      as k5's B operand).  grid (8,4): b, 64-row tile. 4 waves of 64x64.
// ---------------------------------------------------------------------------
__global__ __launch_bounds__(256) void k4b_buildM(const _Float16* __restrict__ Wc16,
                                                  const _Float16* __restrict__ WoBs,
                                                  _Float16* __restrict__ MT) {
    int b    = blockIdx.x;
    int row0 = blockIdx.y * 64;
    int wave = threadIdx.x >> 6, lane = threadIdx.x & 63;
    int lr = lane & 15, lg = lane >> 4;
    int col0 = wave * 64;
    const _Float16* Bb = WoBs + (size_t)b * 256 * 256;

    f32x4 acc[4][4] = {};
    for (int kk = 0; kk < 256; kk += 32) {
        f16x8 af[4], bf[4];
        #pragma unroll
        for (int t = 0; t < 4; ++t)
            af[t] = *(const f16x8*)(Wc16 + (size_t)(row0 + t * 16 + lr) * 256 + kk + lg * 8);
        #pragma unroll
        for (int t = 0; t < 4; ++t)
            bf[t] = *(const f16x8*)(Bb + (size_t)(col0 + t * 16 + lr) * 256 + kk + lg * 8);
        #pragma unroll
        for (int rt = 0; rt < 4; ++rt)
            #pragma unroll
            for (int ct = 0; ct < 4; ++ct)
                acc[rt][ct] = __builtin_amdgcn_mfma_f32_16x16x32_f16(af[rt], bf[ct], acc[rt][ct], 0, 0, 0);
    }
    // D[row=i][col=n]; lane holds col=lr, rows lg*4+r  ->  MT[b][n][i], i contig
    #pragma unroll
    for (int ct = 0; ct < 4; ++ct) {
        int n = col0 + ct * 16 + lr;
        #pragma unroll
        for (int rt = 0; rt < 4; ++rt) {
            int i0 = row0 + rt * 16 + lg * 4;
            f16x4 h;
            h[0] = (_Float16)acc[rt][ct][0]; h[1] = (_Float16)acc[rt][ct][1];
            h[2] = (_Float16)acc[rt][ct][2]; h[3] = (_Float16)acc[rt][ct][3];
            *(f16x4*)(MT + ((size_t)(b * 256 + n)) * 256 + i0) = h;
        }
    }
}

// ---------------------------------------------------------------------------
// K5: main GEMM.  out[b] = x[b] @ M_b + v_b   (131072 x 256 x 256), f16 MFMA,
// x converted f32->f16 on the fly. LDS-free; B frags direct from L2-resident MT.
// Block: 64 rows x 256 cols, 4 waves of 64x64.
// ---------------------------------------------------------------------------
__global__ __launch_bounds__(256) void k5_main(const float* __restrict__ x,
                                               const _Float16* __restrict__ MT,
                                               const float* __restrict__ v,
                                               float* __restrict__ out) {
    int bid  = blockIdx.x;               // 0..2047
    int b    = bid >> 8;
    int row0 = bid * 64;                 // global row in [0, 131072)
    int wave = threadIdx.x >> 6, lane = threadIdx.x & 63;
    int lr = lane & 15, lg = lane >> 4;
    int col0 = wave * 64;
    const _Float16* Bb = MT + (size_t)b * 256 * 256;

    f32x4 acc[4][4] = {};
    for (int kk = 0; kk < 256; kk += 32) {
        f16x8 af[4], bf[4];
        #pragma unroll
        for (int t = 0; t < 4; ++t) {
            const float* ap = x + (size_t)(row0 + t * 16 + lr) * 256 + kk + lg * 8;
            float4 f0 = *(const float4*)ap;
            float4 f1 = *(const float4*)(ap + 4);
            f16x8 a;
            a[0] = (_Float16)f0.x; a[1] = (_Float16)f0.y;
            a[2] = (_Float16)f0.z; a[3] = (_Float16)f0.w;
            a[4] = (_Float16)f1.x; a[5] = (_Float16)f1.y;
            a[6] = (_Float16)f1.z; a[7] = (_Float16)f1.w;
            af[t] = a;
        }
        #pragma unroll
        for (int t = 0; t < 4; ++t)
            bf[t] = *(const f16x8*)(Bb + (size_t)(col0 + t * 16 + lr) * 256 + kk + lg * 8);
        #pragma unroll
        for (int rt = 0; rt < 4; ++rt)
            #pragma unroll
            for (int ct = 0; ct < 4; ++ct)
                acc[rt][ct] = __builtin_amdgcn_mfma_f32_16x16x32_f16(af[rt], bf[ct], acc[rt][ct], 0, 0, 0);
    }
    #pragma unroll
    for (int ct = 0; ct < 4; ++ct) {
        int n = col0 + ct * 16 + lr;
        float vb = v[b * 256 + n];
        #pragma unroll
        for (int rt = 0; rt < 4; ++rt) {
            int r = row0 + rt * 16 + lg * 4;
            float* o = out + (size_t)r * 256 + n;
            #pragma unroll
            for (int reg = 0; reg < 4; ++reg)
                o[(size_t)reg * 256] = acc[rt][ct][reg] + vb;
        }
    }
}

// ---------------------------------------------------------------------------
extern "C" void kernel_launch(void* const* d_in, const int* in_sizes, int n_in,
                              void* d_out, int out_size, void* d_ws, size_t ws_size,
                              hipStream_t stream) {
    const float* x  = (const float*)d_in[0];
    const float* Wa = (const float*)d_in[1];
    // const float* ba = (const float*)d_in[2];   // cancels in softmax
    const float* Wb = (const float*)d_in[3];
    // const float* bb = (const float*)d_in[4];   // cancels in roll-difference
    const float* Wc = (const float*)d_in[5];
    const float* bc = (const float*)d_in[6];
    const float* Wo = (const float*)d_in[7];
    const float* bo = (const float*)d_in[8];
    float* out = (float*)d_out;

    // Workspace (small buffers only; ~20 MB total):
    char* w = (char*)d_ws;
    _Float16* xp   = (_Float16*)w;  w += (size_t)32768 * 256 * 2;        // 16.8 MB
    _Float16* WabT = (_Float16*)w;  w += (size_t)512 * 256 * 2;          // 256 KB
    _Float16* Wc16 = (_Float16*)w;  w += (size_t)256 * 256 * 2;          // 128 KB
    float*    s    = (float*)w;     w += (size_t)8 * 256 * 4;
    _Float16* WoBs = (_Float16*)w;  w += (size_t)8 * 256 * 256 * 2;      // 1 MB
    _Float16* MT   = (_Float16*)w;  w += (size_t)8 * 256 * 256 * 2;      // 1 MB
    float*    vb   = (float*)w;     w += (size_t)8 * 256 * 4;

    // Large xabT intermediate (67 MB) lives in d_out (134 MB): it is fully
    // consumed by k3 before k5 overwrites d_out with the real output.
    float* xabT = out;

    k1_pool   <<<8192, 256, 0, stream>>>(x, xp);
    k1b_wcvt  <<<768, 256, 0, stream>>>(Wa, Wb, Wc, WabT, Wc16);
    k2_gemm_ab<<<dim3(512, 2), 256, 0, stream>>>(xp, WabT, xabT);
    k3_softmax<<<2048, 256, 0, stream>>>(xabT, s);
    k4a_scale <<<8, 256, 0, stream>>>(Wo, bc, bo, s, WoBs, vb);
    k4b_buildM<<<dim3(8, 4), 256, 0, stream>>>(Wc16, WoBs, MT);
    k5_main   <<<2048, 256, 0, stream>>>(x, MT, vb, out);
}